// Round 8
// baseline (145.394 us; speedup 1.0000x reference)
//
#include <hip/hip_runtime.h>
#include <stdint.h>

#define BB 8
#define NN 2048
#define CC 128
#define DD 32
#define LOG2E 1.44269504088896340736f

typedef __attribute__((ext_vector_type(8))) short short8;
typedef __attribute__((ext_vector_type(4))) short short4v;
typedef __attribute__((ext_vector_type(4))) float f32x4;

#define MFMA(a,b,c) __builtin_amdgcn_mfma_f32_16x16x32_bf16(a,b,c,0,0,0)

// 16x16x16 bf16 MFMA: builtin when available (hazards handled, in-place C/D),
// else inline asm with early-clobber dest + hazard nop.
__device__ __forceinline__ f32x4 MFMA16(short4v a, short4v b, f32x4 c){
#if __has_builtin(__builtin_amdgcn_mfma_f32_16x16x16bf16_1k)
  return __builtin_amdgcn_mfma_f32_16x16x16bf16_1k(a, b, c, 0, 0, 0);
#else
  f32x4 d;
  asm volatile("s_nop 1\n\tv_mfma_f32_16x16x16_bf16 %0, %1, %2, %3\n\ts_nop 4"
               : "=&v"(d) : "v"(a), "v"(b), "v"(c));
  return d;
#endif
}

__device__ __forceinline__ short f2b(float f){
  uint32_t u = __float_as_uint(f);
  uint32_t r = (u + 0x7fffu + ((u >> 16) & 1u)) >> 16;
  return (short)r;
}
__device__ __forceinline__ float b2f(short s){
  uint32_t u = ((uint32_t)(uint16_t)s) << 16;
  return __uint_as_float(u);
}

// ---------------- kernel 1: QKV projections (weights packed from fp32 in-reg) ----------------
// grid 1024 (16 rows/block), wave = 3 output groups. qb pre-scaled by LOG2E.
__global__ __launch_bounds__(256,4) void k_qkv(const float* __restrict__ x,
    const float* __restrict__ Wq, const float* __restrict__ Wk, const float* __restrict__ Wv,
    short* __restrict__ qb, short* __restrict__ kb, short* __restrict__ vt){
  const int tid = threadIdx.x;
  const int wv = tid >> 6, l = tid & 63, lrow = l & 15, lg = l >> 4;
  const int r0 = blockIdx.x*16;
  const int base = wv*3;
  const float* xr = x + (long)(r0 + lrow)*CC;
  short8 a[4];
  #pragma unroll
  for (int ks=0; ks<4; ks++){
    f32x4 u0 = *(const f32x4*)(xr + ks*32 + lg*8);
    f32x4 u1 = *(const f32x4*)(xr + ks*32 + lg*8 + 4);
    short8 t;
    #pragma unroll
    for (int j=0;j<4;j++){ t[j] = f2b(u0[j]); t[4+j] = f2b(u1[j]); }
    a[ks] = t;
  }
  f32x4 acc[3];
  #pragma unroll
  for (int i=0;i<3;i++) acc[i] = f32x4{0.f,0.f,0.f,0.f};
  #pragma unroll
  for (int of=0; of<3; of++){
    const int oo = base + of;
    const int row = oo*16 + lrow;
    const float* Wr = (oo < 2) ? (Wq + row*CC) : (oo < 4) ? (Wk + (row-32)*CC) : (Wv + (row-64)*CC);
    #pragma unroll
    for (int ks=0; ks<4; ks++){
      f32x4 w0 = *(const f32x4*)(Wr + ks*32 + lg*8);
      f32x4 w1 = *(const f32x4*)(Wr + ks*32 + lg*8 + 4);
      short8 bfr;
      #pragma unroll
      for (int j=0;j<4;j++){ bfr[j] = f2b(w0[j]); bfr[4+j] = f2b(w1[j]); }
      acc[of] = MFMA(a[ks], bfr, acc[of]);
    }
  }
  const int b = r0 / NN, nin = r0 % NN;
  #pragma unroll
  for (int of=0; of<3; of++){
    const int oo = base + of;
    const int o = oo*16 + lrow;
    if (oo < 2){
      #pragma unroll
      for (int rr=0; rr<4; rr++) qb[(long)(r0 + lg*4 + rr)*DD + o] = f2b(acc[of][rr]*LOG2E);
    } else if (oo < 4){
      #pragma unroll
      for (int rr=0; rr<4; rr++) kb[(long)(r0 + lg*4 + rr)*DD + (o-32)] = f2b(acc[of][rr]);
    } else {
      short4v s;
      #pragma unroll
      for (int rr=0; rr<4; rr++) s[rr] = f2b(acc[of][rr]);
      *(short4v*)(vt + (long)(b*CC + (o-64))*NN + nin + lg*4) = s;
    }
  }
}

// ---------------- kernel 2: column sums of exp(E), 4-way n-split, XCD-affine ----------------
__global__ __launch_bounds__(256,4) void k_colsum(const short* __restrict__ qb, const short* __restrict__ kb,
                                                  float* __restrict__ csum){
  const int tid = threadIdx.x;
  const int wv = tid >> 6, l = tid & 63, lrow = l & 15, lg = l >> 4;
  const int bq = blockIdx.x & 31;
  const int b = bq >> 2, q = bq & 3;
  const int m0 = (blockIdx.x >> 5)*64 + wv*16;
  short8 afr = *(const short8*)(kb + (long)(b*NN + m0 + lrow)*DD + lg*8);
  const short* qbase = qb + (long)b*NN*DD;
  float sum[4] = {0.f,0.f,0.f,0.f};
  f32x4 z = {0.f,0.f,0.f,0.f};
  const int nbeg = q*512, nend = nbeg + 512;
  #pragma unroll 4
  for (int n0=nbeg; n0<nend; n0+=16){
    short8 bfr = *(const short8*)(qbase + (long)(n0 + lrow)*DD + lg*8);
    f32x4 e = MFMA(afr, bfr, z);
    #pragma unroll
    for (int r=0;r<4;r++) sum[r] += exp2f(e[r]);
  }
  #pragma unroll
  for (int mask=1; mask<16; mask<<=1){
    #pragma unroll
    for (int r=0;r<4;r++) sum[r] += __shfl_xor(sum[r], mask);
  }
  if (lrow == 0){
    #pragma unroll
    for (int r=0;r<4;r++) csum[q*(BB*NN) + b*NN + m0 + lg*4 + r] = sum[r];
  }
}

// ---------------- kernel 3a: attention, key-split waves, P stays in registers ----------------
// grid 1024: id = (b*4+q) + rt*32 (XCD-affine). Block = 64 q-rows; wave kw owns 16 keys,
// iterates 4 row-groups. QK swapped (A=K,B=Q) -> C[key][q] == A-frag of 16x16x16 PV.
__global__ __launch_bounds__(256,2) void k_attn(const short* __restrict__ qb,
    const short* __restrict__ kb, const short* __restrict__ vt, const float* __restrict__ csum,
    short* __restrict__ accPb, float* __restrict__ Lp){
  __shared__ __align__(16) short lds[16896]; // vt 9216 | kb 2560 | sinv 1024 | (Lb @16384) | rb overlays 0..16384
  const int tid = threadIdx.x;
  const int kw = tid >> 6, l = tid & 63, lrow = l & 15, lg = l >> 4;
  const int bq = blockIdx.x & 31;
  const int b = bq >> 2;
  const int quarter = bq & 3;
  const int rt = blockIdx.x >> 5;
  const int n0 = rt*64;
  const short* kbb = kb + (long)b*NN*DD;
  const short* vtb = vt + (long)b*CC*NN;
  float* sinvl = (float*)(lds + 11776);

  short8 qfr[4];
  #pragma unroll
  for (int rg=0; rg<4; rg++)
    qfr[rg] = *(const short8*)(qb + (long)(b*NN + n0 + rg*16 + lrow)*DD + lg*8);

  const int mbase = quarter*512;
  {
    const float* c0p = csum + b*NN + mbase;
    #pragma unroll
    for (int i=tid; i<512; i+=256){
      float s = c0p[i] + c0p[i + BB*NN] + c0p[i + 2*BB*NN] + c0p[i + 3*BB*NN];
      sinvl[i] = __builtin_amdgcn_rcpf(s);
    }
  }

  f32x4 acc[4][8];
  #pragma unroll
  for (int rg=0; rg<4; rg++)
    #pragma unroll
    for (int i=0;i<8;i++) acc[rg][i] = f32x4{0.f,0.f,0.f,0.f};
  float Lacc[4] = {0.f,0.f,0.f,0.f};

  short8 sv[4]; short8 sk[2];
  const int cr = tid >> 1, hf = tid & 1;
  auto loadT = [&](int m0){
    const short* s = vtb + (long)cr*NN + m0 + hf*32;
    sv[0] = *(const short8*)(s);
    sv[1] = *(const short8*)(s+8);
    sv[2] = *(const short8*)(s+16);
    sv[3] = *(const short8*)(s+24);
    if (tid < 128){
      const short* s2 = kbb + (long)(m0 + cr)*DD + hf*16;
      sk[0] = *(const short8*)(s2);
      sk[1] = *(const short8*)(s2+8);
    }
  };
  auto storeT = [&](){
    *(short8*)(lds + cr*72 + hf*32 + 0)  = sv[0];
    *(short8*)(lds + cr*72 + hf*32 + 8)  = sv[1];
    *(short8*)(lds + cr*72 + hf*32 + 16) = sv[2];
    *(short8*)(lds + cr*72 + hf*32 + 24) = sv[3];
    if (tid < 128){
      short* kb_t = lds + 9216;
      *(short8*)(kb_t + cr*40 + hf*16 + 0) = sk[0];
      *(short8*)(kb_t + cr*40 + hf*16 + 8) = sk[1];
    }
  };

  loadT(mbase);
  storeT();
  __syncthreads();

  f32x4 z = {0.f,0.f,0.f,0.f};
  for (int it=0; it<8; it++){
    if (it < 7) loadT(mbase + it*64 + 64);
    // wave's K fragment: A[key=kw*16+lrow][d]
    short8 kfr = *(short8*)(lds + 9216 + (kw*16 + lrow)*40 + lg*8);
    float si[4];
    #pragma unroll
    for (int r=0;r<4;r++) si[r] = sinvl[it*64 + kw*16 + lg*4 + r];
    // V B-frags: B[key=lg*4+j][c=cf*16+lrow] (b64 reads, reused across 4 row-groups)
    short4v vbf[8];
    #pragma unroll
    for (int cf=0; cf<8; cf++)
      vbf[cf] = *(short4v*)(lds + (cf*16 + lrow)*72 + kw*16 + lg*4);
    __builtin_amdgcn_s_setprio(1);
    #pragma unroll
    for (int rg=0; rg<4; rg++){
      f32x4 e = MFMA(kfr, qfr[rg], z);     // C[key][q]: row=lg*4+r=key, col=lrow=q
      float p0 = exp2f(e[0])*si[0], p1 = exp2f(e[1])*si[1];
      float p2 = exp2f(e[2])*si[2], p3 = exp2f(e[3])*si[3];
      Lacc[rg] += (p0+p1) + (p2+p3);
      short4v pa; pa[0]=f2b(p0); pa[1]=f2b(p1); pa[2]=f2b(p2); pa[3]=f2b(p3);
      #pragma unroll
      for (int cf=0; cf<8; cf++)
        acc[rg][cf] = MFMA16(pa, vbf[cf], acc[rg][cf]);
    }
    __builtin_amdgcn_s_setprio(0);
    __syncthreads();
    if (it < 7){
      storeT();
      __syncthreads();
    }
  }

  const long tile = (long)((b*32 + rt)*4 + quarter);

  // ---- L merge: reduce over lg (16 keys of wave), then across the 4 key-waves ----
  float Lr[4];
  #pragma unroll
  for (int rg=0; rg<4; rg++){
    float v = Lacc[rg];
    v += __shfl_xor(v, 16);
    v += __shfl_xor(v, 32);
    Lr[rg] = v;
  }
  float* Lb = (float*)(lds + 16384);
  if (l < 16){
    #pragma unroll
    for (int rg=0; rg<4; rg++) Lb[kw*64 + rg*16 + l] = Lr[rg];
  }
  __syncthreads();
  if (l < 16){
    float s = Lb[kw*16 + l] + Lb[64 + kw*16 + l] + Lb[128 + kw*16 + l] + Lb[192 + kw*16 + l];
    Lp[tile*64 + kw*16 + l] = s;
  }

  // ---- O cross-wave reduction: 2 rounds x 2 chunks (16 rows each), bf16 exchange ----
  for (int round=0; round<2; round++){
    const int c0 = round*2;
    #pragma unroll
    for (int cc=0; cc<2; cc++){
      short* dst = lds + (cc*4 + kw)*2048;
      const int c = c0 + cc;
      #pragma unroll
      for (int cf=0; cf<8; cf++)
        #pragma unroll
        for (int r=0;r<4;r++)
          dst[(lg*4+r)*128 + cf*16 + lrow] = f2b(acc[c][cf][r]);
    }
    __syncthreads();
    {
      const int cc = kw & 1;
      const int row = (kw>>1)*8 + (l>>3);
      const int cb = (l&7)*16;
      const short* src = lds + cc*8192 + row*128 + cb;
      float s[16];
      #pragma unroll
      for (int j=0;j<16;j++) s[j] = 0.f;
      #pragma unroll
      for (int slot=0; slot<4; slot++){
        short8 v0 = *(const short8*)(src + slot*2048);
        short8 v1 = *(const short8*)(src + slot*2048 + 8);
        #pragma unroll
        for (int j=0;j<8;j++){ s[j] += b2f(v0[j]); s[8+j] += b2f(v1[j]); }
      }
      short8 o0, o1;
      #pragma unroll
      for (int j=0;j<8;j++){ o0[j] = f2b(s[j]); o1[j] = f2b(s[8+j]); }
      short* aP = accPb + tile*64*128 + ((c0+cc)*16 + row)*128 + cb;
      *(short8*)aP = o0;
      *(short8*)(aP + 8) = o1;
    }
    __syncthreads();
  }
}

// ---------------- kernel 3b: combine 4 bf16 partials + projection + BN + residual ----------------
// grid 1024; Wp packed from fp32 in-reg; BN scale/shift computed inline.
__global__ __launch_bounds__(256,4) void k_fin(const float* __restrict__ x, const short* __restrict__ accPb,
    const float* __restrict__ Lp, const float* __restrict__ Wp, const float* __restrict__ g,
    const float* __restrict__ bt, const float* __restrict__ mu, const float* __restrict__ vr,
    float* __restrict__ out){
  __shared__ __align__(16) short dl[16*136];
  __shared__ float linv_s[16];
  const int tid = threadIdx.x;
  const int wv = tid >> 6, l = tid & 63, lrow = l & 15, lg = l >> 4;
  const int b = blockIdx.x >> 7;
  const int rt = blockIdx.x & 127;
  const int nb = rt*16;
  const long tileIdx = (long)(b*32 + (rt>>2))*4;
  const int rowoff = (rt&3)*16;

  if (tid < 16){
    float Ls = Lp[(tileIdx+0)*64 + rowoff + tid] + Lp[(tileIdx+1)*64 + rowoff + tid]
             + Lp[(tileIdx+2)*64 + rowoff + tid] + Lp[(tileIdx+3)*64 + rowoff + tid];
    linv_s[tid] = __builtin_amdgcn_rcpf(1e-9f + Ls);
  }

  const int row_l = tid >> 4;
  const int c0 = (tid & 15)*8;
  float a[8];
  #pragma unroll
  for (int j=0;j<8;j++) a[j] = 0.f;
  #pragma unroll
  for (int p=0;p<4;p++){
    short8 v = *(const short8*)(accPb + (tileIdx+p)*64*128 + (rowoff+row_l)*128 + c0);
    #pragma unroll
    for (int j=0;j<8;j++) a[j] += b2f(v[j]);
  }
  const float* xr = x + ((long)(b*NN + nb + row_l))*CC + c0;
  f32x4 x0 = *(const f32x4*)(xr);
  f32x4 x1 = *(const f32x4*)(xr + 4);
  __syncthreads();
  {
    const float li = linv_s[row_l];
    short4v d0, d1;
    #pragma unroll
    for (int j=0;j<4;j++){
      d0[j] = f2b(x0[j] - a[j]*li);
      d1[j] = f2b(x1[j] - a[4+j]*li);
    }
    *(short4v*)(dl + row_l*136 + c0) = d0;
    *(short4v*)(dl + row_l*136 + c0 + 4) = d1;
  }
  __syncthreads();

  f32x4 yac[2];
  yac[0] = f32x4{0.f,0.f,0.f,0.f};
  yac[1] = f32x4{0.f,0.f,0.f,0.f};
  #pragma unroll
  for (int ks=0; ks<4; ks++){
    short8 da = *(short8*)(dl + lrow*136 + ks*32 + lg*8);
    #pragma unroll
    for (int of=0; of<2; of++){
      const float* wr = Wp + ((wv*2+of)*16 + lrow)*CC + ks*32 + lg*8;
      f32x4 w0 = *(const f32x4*)(wr);
      f32x4 w1 = *(const f32x4*)(wr + 4);
      short8 wfr;
      #pragma unroll
      for (int j=0;j<4;j++){ wfr[j] = f2b(w0[j]); wfr[4+j] = f2b(w1[j]); }
      yac[of] = MFMA(da, wfr, yac[of]);
    }
  }
  float* ob = out + ((long)(b*NN + nb))*CC;
  const float* xb = x + ((long)(b*NN + nb))*CC;
  #pragma unroll
  for (int of=0; of<2; of++){
    const int o = (wv*2+of)*16 + lrow;
    const float sc = g[o] * rsqrtf(vr[o] + 1e-5f);
    const float sh = bt[o] - mu[o]*sc;
    #pragma unroll
    for (int r=0;r<4;r++){
      float y = yac[of][r]*sc + sh;
      y = (y >= 0.f) ? y : 0.01f*y;
      ob[(lg*4+r)*CC + o] = y + xb[(lg*4+r)*CC + o];
    }
  }
}

extern "C" void kernel_launch(void* const* d_in, const int* in_sizes, int n_in,
                              void* d_out, int out_size, void* d_ws, size_t ws_size,
                              hipStream_t stream) {
  const float* x  = (const float*)d_in[0];
  const float* Wq = (const float*)d_in[1];
  const float* Wk = (const float*)d_in[2];
  const float* Wv = (const float*)d_in[3];
  const float* Wp = (const float*)d_in[4];
  const float* g  = (const float*)d_in[5];
  const float* bt = (const float*)d_in[6];
  const float* mu = (const float*)d_in[7];
  const float* vr = (const float*)d_in[8];
  float* out = (float*)d_out;

  char* ws = (char*)d_ws;
  short* qb    = (short*)(ws + 98304);              // 1 MB
  short* kb    = (short*)(ws + 1146880);            // 1 MB
  short* vt    = (short*)(ws + 2195456);            // 4 MB
  float* csum  = (float*)(ws + 6389760);            // 256 KB
  float* Lp    = (float*)(ws + 6651904);            // 256 KB
  short* accPb = (short*)(ws + 6914048);            // 16.78 MB

  k_qkv<<<1024, 256, 0, stream>>>(x, Wq, Wk, Wv, qb, kb, vt);
  k_colsum<<<1024, 256, 0, stream>>>(qb, kb, csum);
  k_attn<<<1024, 256, 0, stream>>>(qb, kb, vt, csum, accPb, Lp);
  k_fin<<<1024, 256, 0, stream>>>(x, accPb, Lp, Wp, g, bt, mu, vr, out);
}

// Round 9
// 131.853 us; speedup vs baseline: 1.1027x; 1.1027x over previous
//
#include <hip/hip_runtime.h>
#include <stdint.h>

#define BB 8
#define NN 2048
#define CC 128
#define DD 32
#define LOG2E 1.44269504088896340736f

typedef __attribute__((ext_vector_type(8))) short short8;
typedef __attribute__((ext_vector_type(4))) short short4v;
typedef __attribute__((ext_vector_type(4))) float f32x4;

#define MFMA(a,b,c) __builtin_amdgcn_mfma_f32_16x16x32_bf16(a,b,c,0,0,0)

__device__ __forceinline__ short f2b(float f){
  uint32_t u = __float_as_uint(f);
  uint32_t r = (u + 0x7fffu + ((u >> 16) & 1u)) >> 16;
  return (short)r;
}
__device__ __forceinline__ float b2f(short s){
  uint32_t u = ((uint32_t)(uint16_t)s) << 16;
  return __uint_as_float(u);
}

// ---------------- kernel 0: pack weights, fold BN ----------------
__global__ void k_pack(const float* __restrict__ Wq, const float* __restrict__ Wk,
                       const float* __restrict__ Wv, const float* __restrict__ Wp,
                       const float* __restrict__ g, const float* __restrict__ bt,
                       const float* __restrict__ mu, const float* __restrict__ vr,
                       short* __restrict__ wqkv, short* __restrict__ wp,
                       float* __restrict__ scale, float* __restrict__ shift){
  int i = blockIdx.x*256 + threadIdx.x;
  if (i < 192*128){
    int r = i >> 7, c = i & 127;
    float w = (r < 32) ? Wq[r*128+c] : (r < 64) ? Wk[(r-32)*128+c] : Wv[(r-64)*128+c];
    wqkv[i] = f2b(w);
  }
  if (i < 128*128) wp[i] = f2b(Wp[i]);
  if (i < 128){
    float s = g[i] * rsqrtf(vr[i] + 1e-5f);
    scale[i] = s;
    shift[i] = bt[i] - mu[i]*s;
  }
}

// ---------------- kernel 1: QKV projections, grid 1024 (16 rows/block) ----------------
// qb pre-scaled by LOG2E.
__global__ __launch_bounds__(256,4) void k_qkv(const float* __restrict__ x, const short* __restrict__ wqkv,
    short* __restrict__ qb, short* __restrict__ kb, short* __restrict__ vt){
  const int tid = threadIdx.x;
  const int wv = tid >> 6, l = tid & 63, lrow = l & 15, lg = l >> 4;
  const int r0 = blockIdx.x*16;
  const int base = wv*3;
  const float* xr = x + (long)(r0 + lrow)*CC;
  short8 a[4];
  #pragma unroll
  for (int ks=0; ks<4; ks++){
    f32x4 u0 = *(const f32x4*)(xr + ks*32 + lg*8);
    f32x4 u1 = *(const f32x4*)(xr + ks*32 + lg*8 + 4);
    short8 t;
    #pragma unroll
    for (int j=0;j<4;j++){ t[j] = f2b(u0[j]); t[4+j] = f2b(u1[j]); }
    a[ks] = t;
  }
  f32x4 acc[3];
  #pragma unroll
  for (int i=0;i<3;i++) acc[i] = f32x4{0.f,0.f,0.f,0.f};
  #pragma unroll
  for (int of=0; of<3; of++){
    #pragma unroll
    for (int ks=0; ks<4; ks++){
      short8 bfr = *(const short8*)(wqkv + ((base+of)*16 + lrow)*CC + ks*32 + lg*8);
      acc[of] = MFMA(a[ks], bfr, acc[of]);
    }
  }
  const int b = r0 / NN, nin = r0 % NN;
  #pragma unroll
  for (int of=0; of<3; of++){
    const int oo = base + of;
    const int o = oo*16 + lrow;
    if (oo < 2){
      #pragma unroll
      for (int rr=0; rr<4; rr++) qb[(long)(r0 + lg*4 + rr)*DD + o] = f2b(acc[of][rr]*LOG2E);
    } else if (oo < 4){
      #pragma unroll
      for (int rr=0; rr<4; rr++) kb[(long)(r0 + lg*4 + rr)*DD + (o-32)] = f2b(acc[of][rr]);
    } else {
      short4v s;
      #pragma unroll
      for (int rr=0; rr<4; rr++) s[rr] = f2b(acc[of][rr]);
      *(short4v*)(vt + (long)(b*CC + (o-64))*NN + nin + lg*4) = s;
    }
  }
}

// ---------------- kernel 2: column sums of exp(E), 4-way n-split, XCD-affine ----------------
__global__ __launch_bounds__(256,4) void k_colsum(const short* __restrict__ qb, const short* __restrict__ kb,
                                                  float* __restrict__ csum){
  const int tid = threadIdx.x;
  const int wv = tid >> 6, l = tid & 63, lrow = l & 15, lg = l >> 4;
  const int bq = blockIdx.x & 31;
  const int b = bq >> 2, q = bq & 3;
  const int m0 = (blockIdx.x >> 5)*64 + wv*16;
  short8 afr = *(const short8*)(kb + (long)(b*NN + m0 + lrow)*DD + lg*8);
  const short* qbase = qb + (long)b*NN*DD;
  float sum[4] = {0.f,0.f,0.f,0.f};
  f32x4 z = {0.f,0.f,0.f,0.f};
  const int nbeg = q*512, nend = nbeg + 512;
  #pragma unroll 4
  for (int n0=nbeg; n0<nend; n0+=16){
    short8 bfr = *(const short8*)(qbase + (long)(n0 + lrow)*DD + lg*8);
    f32x4 e = MFMA(afr, bfr, z);
    #pragma unroll
    for (int r=0;r<4;r++) sum[r] += exp2f(e[r]);
  }
  #pragma unroll
  for (int mask=1; mask<16; mask<<=1){
    #pragma unroll
    for (int r=0;r<4;r++) sum[r] += __shfl_xor(sum[r], mask);
  }
  if (lrow == 0){
    #pragma unroll
    for (int r=0;r<4;r++) csum[q*(BB*NN) + b*NN + m0 + lg*4 + r] = sum[r];
  }
}

// ---------------- kernel 3a: attention, 32 rows/wave (B-frags shared across 2 row-groups) ----------------
// grid 512: id = (b*4+q) + rt*32 (XCD-affine), rt in 0..15, block = 128 q-rows.
__global__ __launch_bounds__(256,2) void k_attn(const short* __restrict__ qb,
    const short* __restrict__ kb, const short* __restrict__ vt, const float* __restrict__ csum,
    short* __restrict__ accPb, float* __restrict__ Lp){
  __shared__ __align__(16) short lds[22016]; // V 0..9216 | K 9216..11776 | P 11776..20992 (4w x [32][72]) | sinv 20992..22016
  const int tid = threadIdx.x;
  const int wv = tid >> 6, l = tid & 63, lrow = l & 15, lg = l >> 4;
  const int bq = blockIdx.x & 31;
  const int b = bq >> 2;
  const int quarter = bq & 3;
  const int rt = blockIdx.x >> 5;
  const int n0 = rt*128 + wv*32;
  const short* kbb = kb + (long)b*NN*DD;
  const short* vtb = vt + (long)b*CC*NN;
  float* sinvl = (float*)(lds + 20992);

  short8 qfr[2];
  #pragma unroll
  for (int rg=0; rg<2; rg++)
    qfr[rg] = *(const short8*)(qb + (long)(b*NN + n0 + rg*16 + lrow)*DD + lg*8);

  const int mbase = quarter*512;
  {
    const float* c0p = csum + b*NN + mbase;
    #pragma unroll
    for (int i=tid; i<512; i+=256){
      float s = c0p[i] + c0p[i + BB*NN] + c0p[i + 2*BB*NN] + c0p[i + 3*BB*NN];
      sinvl[i] = __builtin_amdgcn_rcpf(s);
    }
  }

  f32x4 acc[2][8];
  #pragma unroll
  for (int rg=0; rg<2; rg++)
    #pragma unroll
    for (int i=0;i<8;i++) acc[rg][i] = f32x4{0.f,0.f,0.f,0.f};
  float L[2][4] = {{0.f,0.f,0.f,0.f},{0.f,0.f,0.f,0.f}};

  short8 sv[4]; short8 sk[2];
  const int cr = tid >> 1, hf = tid & 1;
  auto loadT = [&](int m0){
    const short* s = vtb + (long)cr*NN + m0 + hf*32;
    sv[0] = *(const short8*)(s);
    sv[1] = *(const short8*)(s+8);
    sv[2] = *(const short8*)(s+16);
    sv[3] = *(const short8*)(s+24);
    if (tid < 128){
      const short* s2 = kbb + (long)(m0 + cr)*DD + hf*16;
      sk[0] = *(const short8*)(s2);
      sk[1] = *(const short8*)(s2+8);
    }
  };
  auto storeT = [&](){
    *(short8*)(lds + cr*72 + hf*32 + 0)  = sv[0];
    *(short8*)(lds + cr*72 + hf*32 + 8)  = sv[1];
    *(short8*)(lds + cr*72 + hf*32 + 16) = sv[2];
    *(short8*)(lds + cr*72 + hf*32 + 24) = sv[3];
    if (tid < 128){
      short* kb_t = lds + 9216;
      *(short8*)(kb_t + cr*40 + hf*16 + 0) = sk[0];
      *(short8*)(kb_t + cr*40 + hf*16 + 8) = sk[1];
    }
  };

  loadT(mbase);
  storeT();
  __syncthreads();

  short* pl = lds + 11776 + wv*2304;
  f32x4 z = {0.f,0.f,0.f,0.f};
  for (int it=0; it<8; it++){
    if (it < 7) loadT(mbase + it*64 + 64);
    short* kb_t = lds + 9216;
    // K B-frags, read once, shared across both row-groups
    short8 kf[4];
    #pragma unroll
    for (int mt=0; mt<4; mt++)
      kf[mt] = *(short8*)(kb_t + (mt*16 + lrow)*40 + lg*8);
    #pragma unroll
    for (int rg=0; rg<2; rg++){
      #pragma unroll
      for (int mt=0; mt<4; mt++){
        f32x4 e = MFMA(qfr[rg], kf[mt], z);
        float si = sinvl[it*64 + mt*16 + lrow];
        float p0 = exp2f(e[0])*si, p1 = exp2f(e[1])*si;
        float p2 = exp2f(e[2])*si, p3 = exp2f(e[3])*si;
        L[rg][0] += p0; L[rg][1] += p1; L[rg][2] += p2; L[rg][3] += p3;
        pl[(rg*16 + lg*4 + 0)*72 + mt*16 + lrow] = f2b(p0);
        pl[(rg*16 + lg*4 + 1)*72 + mt*16 + lrow] = f2b(p1);
        pl[(rg*16 + lg*4 + 2)*72 + mt*16 + lrow] = f2b(p2);
        pl[(rg*16 + lg*4 + 3)*72 + mt*16 + lrow] = f2b(p3);
      }
    }
    __builtin_amdgcn_s_setprio(1);
    #pragma unroll
    for (int ks=0; ks<2; ks++){
      short8 pa0 = *(short8*)(pl + (lrow)*72 + ks*32 + lg*8);
      short8 pa1 = *(short8*)(pl + (16 + lrow)*72 + ks*32 + lg*8);
      #pragma unroll
      for (int cf=0; cf<8; cf++){
        short8 vb_ = *(short8*)(lds + (cf*16 + lrow)*72 + ks*32 + lg*8);
        acc[0][cf] = MFMA(pa0, vb_, acc[0][cf]);
        acc[1][cf] = MFMA(pa1, vb_, acc[1][cf]);
      }
    }
    __builtin_amdgcn_s_setprio(0);
    __syncthreads();
    if (it < 7){
      storeT();
      __syncthreads();
    }
  }

  // ---- L reduce over the 16 key-columns (lrow lanes), write per-row partial ----
  #pragma unroll
  for (int mask=1; mask<16; mask<<=1){
    #pragma unroll
    for (int rg=0; rg<2; rg++)
      #pragma unroll
      for (int r=0;r<4;r++) L[rg][r] += __shfl_xor(L[rg][r], mask);
  }
  const long tile = (long)((b*16 + rt)*4 + quarter);
  if (lrow == 0){
    #pragma unroll
    for (int rg=0; rg<2; rg++)
      #pragma unroll
      for (int r=0;r<4;r++)
        Lp[tile*128 + wv*32 + rg*16 + lg*4 + r] = L[rg][r];
  }

  // ---- O partial store (bf16) ----
  short* aP = accPb + tile*128*128;
  #pragma unroll
  for (int rg=0; rg<2; rg++)
    #pragma unroll
    for (int cf=0; cf<8; cf++)
      #pragma unroll
      for (int r=0;r<4;r++)
        aP[(wv*32 + rg*16 + lg*4 + r)*128 + cf*16 + lrow] = f2b(acc[rg][cf][r]);
}

// ---------------- kernel 3b: combine 4 bf16 partials + projection + BN + residual ----------------
// grid 1024: b(3b) | rt(7b of 16 rows). Tiles are 128 rows x 4 quarters.
__global__ __launch_bounds__(256,4) void k_fin(const float* __restrict__ x, const short* __restrict__ accPb,
    const float* __restrict__ Lp, const short* __restrict__ wp, const float* __restrict__ scale,
    const float* __restrict__ shift, float* __restrict__ out){
  __shared__ __align__(16) short dl[16*136];
  __shared__ float linv_s[16];
  const int tid = threadIdx.x;
  const int wv = tid >> 6, l = tid & 63, lrow = l & 15, lg = l >> 4;
  const int b = blockIdx.x >> 7;
  const int rt = blockIdx.x & 127;
  const int nb = rt*16;
  const long tileIdx = (long)(b*16 + (rt>>3))*4;
  const int rowoff = (rt&7)*16;

  if (tid < 16){
    float Ls = Lp[(tileIdx+0)*128 + rowoff + tid] + Lp[(tileIdx+1)*128 + rowoff + tid]
             + Lp[(tileIdx+2)*128 + rowoff + tid] + Lp[(tileIdx+3)*128 + rowoff + tid];
    linv_s[tid] = __builtin_amdgcn_rcpf(1e-9f + Ls);
  }

  const int row_l = tid >> 4;
  const int c0 = (tid & 15)*8;
  float a[8];
  #pragma unroll
  for (int j=0;j<8;j++) a[j] = 0.f;
  #pragma unroll
  for (int p=0;p<4;p++){
    short8 v = *(const short8*)(accPb + (tileIdx+p)*128*128 + (rowoff+row_l)*128 + c0);
    #pragma unroll
    for (int j=0;j<8;j++) a[j] += b2f(v[j]);
  }
  const float* xr = x + ((long)(b*NN + nb + row_l))*CC + c0;
  f32x4 x0 = *(const f32x4*)(xr);
  f32x4 x1 = *(const f32x4*)(xr + 4);
  __syncthreads();
  {
    const float li = linv_s[row_l];
    short4v d0, d1;
    #pragma unroll
    for (int j=0;j<4;j++){
      d0[j] = f2b(x0[j] - a[j]*li);
      d1[j] = f2b(x1[j] - a[4+j]*li);
    }
    *(short4v*)(dl + row_l*136 + c0) = d0;
    *(short4v*)(dl + row_l*136 + c0 + 4) = d1;
  }
  __syncthreads();

  f32x4 yac[2];
  yac[0] = f32x4{0.f,0.f,0.f,0.f};
  yac[1] = f32x4{0.f,0.f,0.f,0.f};
  #pragma unroll
  for (int ks=0; ks<4; ks++){
    short8 da = *(short8*)(dl + lrow*136 + ks*32 + lg*8);
    #pragma unroll
    for (int of=0; of<2; of++){
      short8 wfr = *(const short8*)(wp + ((wv*2+of)*16 + lrow)*CC + ks*32 + lg*8);
      yac[of] = MFMA(da, wfr, yac[of]);
    }
  }
  float* ob = out + ((long)(b*NN + nb))*CC;
  const float* xb = x + ((long)(b*NN + nb))*CC;
  #pragma unroll
  for (int of=0; of<2; of++){
    const int o = (wv*2+of)*16 + lrow;
    const float sc = scale[o], sh = shift[o];
    #pragma unroll
    for (int r=0;r<4;r++){
      float y = yac[of][r]*sc + sh;
      y = (y >= 0.f) ? y : 0.01f*y;
      ob[(lg*4+r)*CC + o] = y + xb[(lg*4+r)*CC + o];
    }
  }
}

extern "C" void kernel_launch(void* const* d_in, const int* in_sizes, int n_in,
                              void* d_out, int out_size, void* d_ws, size_t ws_size,
                              hipStream_t stream) {
  const float* x  = (const float*)d_in[0];
  const float* Wq = (const float*)d_in[1];
  const float* Wk = (const float*)d_in[2];
  const float* Wv = (const float*)d_in[3];
  const float* Wp = (const float*)d_in[4];
  const float* g  = (const float*)d_in[5];
  const float* bt = (const float*)d_in[6];
  const float* mu = (const float*)d_in[7];
  const float* vr = (const float*)d_in[8];
  float* out = (float*)d_out;

  char* ws = (char*)d_ws;
  short* wqkv  = (short*)(ws + 0);                  // 49152
  short* wp    = (short*)(ws + 49152);              // 32768
  float* scale = (float*)(ws + 81920);              // 512
  float* shift = (float*)(ws + 82432);              // 512
  short* qb    = (short*)(ws + 98304);              // 1 MB
  short* kb    = (short*)(ws + 1146880);            // 1 MB
  short* vt    = (short*)(ws + 2195456);            // 4 MB
  float* csum  = (float*)(ws + 6389760);            // 256 KB
  float* Lp    = (float*)(ws + 6651904);            // 512*128*4 = 256 KB
  short* accPb = (short*)(ws + 6914048);            // 512*128*128*2 = 16.78 MB

  k_pack<<<96, 256, 0, stream>>>(Wq, Wk, Wv, Wp, g, bt, mu, vr, wqkv, wp, scale, shift);
  k_qkv<<<1024, 256, 0, stream>>>(x, wqkv, qb, kb, vt);
  k_colsum<<<1024, 256, 0, stream>>>(qb, kb, csum);
  k_attn<<<512, 256, 0, stream>>>(qb, kb, vt, csum, accPb, Lp);
  k_fin<<<1024, 256, 0, stream>>>(x, accPb, Lp, wp, scale, shift, out);
}